// Round 1
// baseline (155.703 us; speedup 1.0000x reference)
//
#include <hip/hip_runtime.h>
#include <hip/hip_cooperative_groups.h>
#include <math.h>

namespace cg = cooperative_groups;

namespace {

constexpr int kB  = 4;
constexpr int kS  = 128;
constexpr int kD  = 256;
constexpr int kH  = 8;
constexpr int kK  = 256;
constexpr float kPi    = 3.14159265358979323846f;
constexpr float kScale = 0.17677669529663687f;  // 1/sqrt(32)

typedef __bf16 bf16x8 __attribute__((ext_vector_type(8)));
typedef float  f32x4  __attribute__((ext_vector_type(4)));
typedef float  f32x8  __attribute__((ext_vector_type(8)));

// split 8 consecutive fp32 into bf16 hi/lo fragments (in registers)
__device__ inline void split8(const float* __restrict__ p, bf16x8& hi, bf16x8& lo) {
  const f32x8 v = *(const f32x8*)p;
#pragma unroll
  for (int e = 0; e < 8; ++e) {
    const __bf16 h = (__bf16)v[e];
    hi[e] = h;
    lo[e] = (__bf16)(v[e] - (float)h);
  }
}

// ---- single cooperative kernel: QKV -> sync -> attn -> sync -> out GEMM ----
// Phase mapping:
//  P1 (QKV): 640 wave-jobs over 1024 waves, wave-major (job = wave*256+blockId)
//            so all waves in a block share m-tile (mx = blockId&31) for L1 reuse.
//            seg = job>>5: seg<16 -> V cols (ny=seg>>2, w=seg&3); seg 16..19 ->
//            compact Qsub/Ksub (w<2 Q, else K; col c=(w&1)*16+ln, wrow=head*32+wire).
//  P2 (attn): block = (i-tile = blockIdx.x, bh = blockIdx.y), exact prior K2 body.
//  P3 (out):  512 wave-jobs (mx = job&31, col-tile ct = job>>5).
// Arithmetic identical to the 3-kernel version (bit-identical results).
__global__ void __launch_bounds__(256) fused_all(
    const float* __restrict__ x,
    const float* __restrict__ Wq, const float* __restrict__ bq,
    const float* __restrict__ Wk, const float* __restrict__ bk,
    const float* __restrict__ Wv, const float* __restrict__ bv,
    const float* __restrict__ Wo, const float* __restrict__ bo,
    const float* __restrict__ params,
    float* __restrict__ V, float* __restrict__ Qs, float* __restrict__ Ks,
    __bf16* __restrict__ aohi, __bf16* __restrict__ aolo,
    float* __restrict__ out) {
  __shared__ float kC[3][kS];
  __shared__ float Vl[kS][32];
  __shared__ float pl[16][kS + 4];
  __shared__ float qA[16][3], qB[16][3];

  cg::grid_group grid = cg::this_grid();

  const int tid  = threadIdx.x;
  const int wave = tid >> 6;
  const int lane = tid & 63;
  const int ln = lane & 15;
  const int qd = lane >> 4;
  const int blockId = blockIdx.y * gridDim.x + blockIdx.x;  // 0..255

  // ---------------- phase 1: QKV projection ----------------
  {
    const int job = wave * 256 + blockId;  // 0..1023
    if (job < 640) {
      const int mx  = job & 31;
      const int seg = job >> 5;       // 0..19
      const int ny  = seg >> 2;       // 0..4
      const int w   = seg & 3;
      const int m0  = mx * 16;

      const float* W;
      const float* bias;
      int wrow;
      if (ny < 4) {
        W = Wv; bias = bv;
        wrow = ny * 64 + w * 16 + ln;
      } else {
        const int c = (w & 1) * 16 + ln;   // compact col 0..31
        wrow = (c >> 2) * 32 + (c & 3);    // head*32 + wire
        if (w < 2) { W = Wq; bias = bq; } else { W = Wk; bias = bk; }
      }

      const float* ap = x + (m0 + ln) * kK + qd * 8;
      const float* bp = W + wrow * kK + qd * 8;

      f32x4 acc = {0.f, 0.f, 0.f, 0.f};
#pragma unroll
      for (int kc = 0; kc < kK; kc += 32) {
        bf16x8 Ah, Al, Bh, Bl;
        split8(ap + kc, Ah, Al);
        split8(bp + kc, Bh, Bl);
        acc = __builtin_amdgcn_mfma_f32_16x16x32_bf16(Ah, Bh, acc, 0, 0, 0);
        acc = __builtin_amdgcn_mfma_f32_16x16x32_bf16(Ah, Bl, acc, 0, 0, 0);
        acc = __builtin_amdgcn_mfma_f32_16x16x32_bf16(Al, Bh, acc, 0, 0, 0);
      }
      const float bvv = bias[wrow];
      const int row0 = m0 + qd * 4;
      if (ny < 4) {
        const int col = ny * 64 + w * 16 + ln;
#pragma unroll
        for (int r = 0; r < 4; ++r)
          V[(row0 + r) * kD + col] = acc[r] + bvv;
      } else {
        const int c = (w & 1) * 16 + ln;
        float* o = (w < 2) ? Qs : Ks;
#pragma unroll
        for (int r = 0; r < 4; ++r)
          o[(row0 + r) * 32 + c] = acc[r] + bvv;
      }
    }
  }
  grid.sync();

  // ---------------- phase 2: prep + scores + softmax + attn@V ----------------
  {
    const int bh = blockIdx.y;
    const int i0 = blockIdx.x * 16;
    const int b  = bh >> 3;
    const int h  = bh & 7;

    if (tid < kS) {  // K-prep: one j per thread
      const float4 kv = *(const float4*)(Ks + (b * kS + tid) * 32 + h * 4);
      const float kmn = fminf(fminf(kv.x, kv.y), fminf(kv.z, kv.w));
      const float kmx = fmaxf(fmaxf(kv.x, kv.y), fmaxf(kv.z, kv.w));
      const float ksc = kPi / (kmx - kmn + 1e-8f);
      kC[0][tid] = cosf((kv.y - kmn) * ksc);
      kC[1][tid] = cosf((kv.z - kmn) * ksc);
      kC[2][tid] = cosf((kv.w - kmn) * ksc);
    } else if (tid < kS + 16) {  // Q-prep: one i per thread
      const int il = tid - kS;
      const float4 qv = *(const float4*)(Qs + (b * kS + i0 + il) * 32 + h * 4);
      const float qmn = fminf(fminf(qv.x, qv.y), fminf(qv.z, qv.w));
      const float qmx = fmaxf(fmaxf(qv.x, qv.y), fmaxf(qv.z, qv.w));
      const float qsc = kPi / (qmx - qmn + 1e-8f);
      const float qn[3] = {(qv.y - qmn) * qsc, (qv.z - qmn) * qsc, (qv.w - qmn) * qsc};
#pragma unroll
      for (int w = 0; w < 3; ++w) {
        const float th = params[w + 1];
        qA[il][w] = cosf(th) * cosf(qn[w]);
        qB[il][w] = sinf(th) * sinf(qn[w]);
      }
    }
    {  // V tile load (all threads)
      const int j0 = tid >> 5, d = tid & 31;
#pragma unroll
      for (int r = 0; r < 16; ++r) {
        const int j = r * 8 + j0;
        Vl[j][d] = V[(b * kS + j) * kD + h * 32 + d];
      }
    }
    __syncthreads();

    const int i_loc = tid >> 4;   // 0..15
    const int jl    = tid & 15;   // 16 threads per i-row
    const float A1 = qA[i_loc][0], A2 = qA[i_loc][1], A3 = qA[i_loc][2];
    const float B1 = qB[i_loc][0], B2 = qB[i_loc][1], B3 = qB[i_loc][2];

    float e[8];
    float mx = -1e30f;
#pragma unroll
    for (int jj = 0; jj < 8; ++jj) {
      const int j = jl + 16 * jj;
      const float v = (A1 - B1 * kC[0][j]) * (A2 - B2 * kC[1][j]) *
                      (A3 - B3 * kC[2][j]) * kScale;
      e[jj] = v;
      mx = fmaxf(mx, v);
    }
#pragma unroll
    for (int m = 1; m < 16; m <<= 1) mx = fmaxf(mx, __shfl_xor(mx, m, 16));
    float sum = 0.f;
#pragma unroll
    for (int jj = 0; jj < 8; ++jj) { e[jj] = expf(e[jj] - mx); sum += e[jj]; }
#pragma unroll
    for (int m = 1; m < 16; m <<= 1) sum += __shfl_xor(sum, m, 16);
    const float inv = 1.f / sum;
#pragma unroll
    for (int jj = 0; jj < 8; ++jj) pl[i_loc][jl + 16 * jj] = e[jj] * inv;
    __syncthreads();

    // attn @ V: thread -> (i = tid>>4, d0 = tid&15, and d0+16)
    const int d0 = tid & 15;
    float a0 = 0.f, a1 = 0.f;
#pragma unroll 4
    for (int j = 0; j < kS; ++j) {
      const float p = pl[i_loc][j];
      a0 = fmaf(p, Vl[j][d0], a0);
      a1 = fmaf(p, Vl[j][d0 + 16], a1);
    }
    const int base = (b * kS + i0 + i_loc) * kD + h * 32;
    const __bf16 h0 = (__bf16)a0;
    const __bf16 h1 = (__bf16)a1;
    aohi[base + d0]      = h0;
    aolo[base + d0]      = (__bf16)(a0 - (float)h0);
    aohi[base + d0 + 16] = h1;
    aolo[base + d0 + 16] = (__bf16)(a1 - (float)h1);
  }
  grid.sync();

  // ---------------- phase 3: out = ao @ Wo^T + bo ----------------
  {
    const int job = wave * 256 + blockId;  // 0..1023
    if (job < 512) {
      const int mx = job & 31;
      const int ct = job >> 5;   // 0..15
      const int m0 = mx * 16;
      const int n0 = ct * 16;

      const __bf16* ap  = aohi + (m0 + ln) * kK + qd * 8;
      const __bf16* alp = aolo + (m0 + ln) * kK + qd * 8;
      const float*  bp  = Wo + (n0 + ln) * kK + qd * 8;

      f32x4 acc = {0.f, 0.f, 0.f, 0.f};
#pragma unroll
      for (int kc = 0; kc < kK; kc += 32) {
        const bf16x8 Ah = *(const bf16x8*)(ap  + kc);
        const bf16x8 Al = *(const bf16x8*)(alp + kc);
        bf16x8 Bh, Bl;
        split8(bp + kc, Bh, Bl);
        acc = __builtin_amdgcn_mfma_f32_16x16x32_bf16(Ah, Bh, acc, 0, 0, 0);
        acc = __builtin_amdgcn_mfma_f32_16x16x32_bf16(Ah, Bl, acc, 0, 0, 0);
        acc = __builtin_amdgcn_mfma_f32_16x16x32_bf16(Al, Bh, acc, 0, 0, 0);
      }
      const int col  = n0 + ln;
      const float bv = bo[col];
      const int row0 = m0 + qd * 4;
#pragma unroll
      for (int r = 0; r < 4; ++r)
        out[(row0 + r) * kD + col] = acc[r] + bv;
    }
  }
}

}  // namespace

extern "C" void kernel_launch(void* const* d_in, const int* in_sizes, int n_in,
                              void* d_out, int out_size, void* d_ws, size_t ws_size,
                              hipStream_t stream) {
  const float* x  = (const float*)d_in[0];
  const float* Wq = (const float*)d_in[1];
  const float* bq = (const float*)d_in[2];
  const float* Wk = (const float*)d_in[3];
  const float* bk = (const float*)d_in[4];
  const float* Wv = (const float*)d_in[5];
  const float* bv = (const float*)d_in[6];
  const float* Wo = (const float*)d_in[7];
  const float* bo = (const float*)d_in[8];
  const float* pr = (const float*)d_in[9];
  float* out = (float*)d_out;

  // -------- workspace layout (floats), all dedicated, no aliasing --------
  float* ws = (float*)d_ws;
  float* V   = ws;               // 131072
  float* Qs  = V + 131072;       // 16384 ([512][32] compact head-wire cols)
  float* Ks  = Qs + 16384;       // 16384
  __bf16* aohi = (__bf16*)(Ks + 16384);  // 131072 bf16
  __bf16* aolo = aohi + 131072;          // 131072 bf16
  // total ~0.9 MB << ws_size

  void* args[] = {(void*)&x,  (void*)&Wq, (void*)&bq, (void*)&Wk, (void*)&bk,
                  (void*)&Wv, (void*)&bv, (void*)&Wo, (void*)&bo, (void*)&pr,
                  (void*)&V,  (void*)&Qs, (void*)&Ks, (void*)&aohi, (void*)&aolo,
                  (void*)&out};
  hipLaunchCooperativeKernel((const void*)fused_all, dim3(8, 32), dim3(256, 1, 1),
                             args, 0, stream);
}

// Round 2
// 97.234 us; speedup vs baseline: 1.6013x; 1.6013x over previous
//
#include <hip/hip_runtime.h>
#include <math.h>

namespace {

constexpr int kS  = 128;
constexpr int kD  = 256;
constexpr int kK  = 256;
constexpr float kPi    = 3.14159265358979323846f;
constexpr float kScale = 0.17677669529663687f;  // 1/sqrt(32)

typedef __bf16 bf16x8 __attribute__((ext_vector_type(8)));
typedef float  f32x4  __attribute__((ext_vector_type(4)));
typedef float  f32x8  __attribute__((ext_vector_type(8)));

// split 8 consecutive fp32 into bf16 hi/lo fragments (in registers)
__device__ inline void split8(const float* __restrict__ p, bf16x8& hi, bf16x8& lo) {
  const f32x8 v = *(const f32x8*)p;
#pragma unroll
  for (int e = 0; e < 8; ++e) {
    const __bf16 h = (__bf16)v[e];
    hi[e] = h;
    lo[e] = (__bf16)(v[e] - (float)h);
  }
}

// ---- single non-cooperative kernel, block = (i-tile, b*8+h), 256 threads ----
// Phase 1: per-(b,h) QKV sub-projection via triple-split bf16 MFMA.
//   Each wave handles 2 m-tiles; per m-tile computes 3 output n-groups at once
//   (V cols 0..15, V cols 16..31, combined K/Q wires) sharing the A-split.
//   Results -> LDS (Vl, ks_l, qs_l). Bit-identical to the 3-kernel version.
// Phase 2: angle prep + closed-form scores + softmax + attn@V (unchanged math),
//   ao kept in LDS (fp32), never touches global.
// Phase 3: per-head partial out GEMM: ao_h(16x32) @ Wo_h^T -> 16x256 partial,
//   bf16 hi/lo split in registers, accumulated into out via f32 atomics.
//   h==0 blocks fold in the bias. out is zeroed by a memset node beforehand.
__global__ void __launch_bounds__(256) fused_one(
    const float* __restrict__ x,
    const float* __restrict__ Wq, const float* __restrict__ bq,
    const float* __restrict__ Wk, const float* __restrict__ bk,
    const float* __restrict__ Wv, const float* __restrict__ bv,
    const float* __restrict__ Wo, const float* __restrict__ bo,
    const float* __restrict__ params,
    float* __restrict__ out) {
  __shared__ float kC[3][kS];
  __shared__ float Vl[kS][32];
  __shared__ float pl[16][kS + 4];
  __shared__ float qA[16][3], qB[16][3];
  __shared__ float ks_l[kS][4];
  __shared__ float qs_l[16][4];
  __shared__ float ao_l[16][36];   // padded: breaks 16-way bank conflict on row reads

  const int tid  = threadIdx.x;
  const int wave = tid >> 6;
  const int lane = tid & 63;
  const int ln = lane & 15;
  const int qd = lane >> 4;
  const int it = blockIdx.x;       // 0..7  i-tile
  const int bh = blockIdx.y;       // 0..31
  const int b  = bh >> 3;
  const int h  = bh & 7;

  // ---------------- phase 1: QKV sub-projection ----------------
  {
    // B-operand rows (fixed per block): V cols h*32+ln / h*32+16+ln,
    // combined KQ tile: ln<4 -> K wire ln, ln in 4..7 -> Q wire ln-4, rest dummy.
    const float* bp0 = Wv + (h * 32 + ln) * kK + qd * 8;
    const float* bp1 = Wv + (h * 32 + 16 + ln) * kK + qd * 8;
    const float* WKQ;
    int wrow;
    float biaskq;
    if (ln < 4)      { WKQ = Wk; wrow = h * 32 + ln;       biaskq = bk[wrow]; }
    else if (ln < 8) { WKQ = Wq; wrow = h * 32 + (ln - 4); biaskq = bq[wrow]; }
    else             { WKQ = Wk; wrow = h * 32 + (ln & 3); biaskq = 0.f; }
    const float* bp2 = WKQ + wrow * kK + qd * 8;
    const float bv0 = bv[h * 32 + ln];
    const float bv1 = bv[h * 32 + 16 + ln];

#pragma unroll
    for (int t = 0; t < 2; ++t) {
      const int mt = wave * 2 + t;   // 0..7
      const float* ap = x + (b * kS + mt * 16 + ln) * kK + qd * 8;
      f32x4 a0v = {0.f, 0.f, 0.f, 0.f};
      f32x4 a1v = {0.f, 0.f, 0.f, 0.f};
      f32x4 a2v = {0.f, 0.f, 0.f, 0.f};
#pragma unroll
      for (int kc = 0; kc < kK; kc += 32) {
        bf16x8 Ah, Al, B0h, B0l, B1h, B1l, B2h, B2l;
        split8(ap + kc, Ah, Al);
        split8(bp0 + kc, B0h, B0l);
        split8(bp1 + kc, B1h, B1l);
        split8(bp2 + kc, B2h, B2l);
        a0v = __builtin_amdgcn_mfma_f32_16x16x32_bf16(Ah, B0h, a0v, 0, 0, 0);
        a0v = __builtin_amdgcn_mfma_f32_16x16x32_bf16(Ah, B0l, a0v, 0, 0, 0);
        a0v = __builtin_amdgcn_mfma_f32_16x16x32_bf16(Al, B0h, a0v, 0, 0, 0);
        a1v = __builtin_amdgcn_mfma_f32_16x16x32_bf16(Ah, B1h, a1v, 0, 0, 0);
        a1v = __builtin_amdgcn_mfma_f32_16x16x32_bf16(Ah, B1l, a1v, 0, 0, 0);
        a1v = __builtin_amdgcn_mfma_f32_16x16x32_bf16(Al, B1h, a1v, 0, 0, 0);
        a2v = __builtin_amdgcn_mfma_f32_16x16x32_bf16(Ah, B2h, a2v, 0, 0, 0);
        a2v = __builtin_amdgcn_mfma_f32_16x16x32_bf16(Ah, B2l, a2v, 0, 0, 0);
        a2v = __builtin_amdgcn_mfma_f32_16x16x32_bf16(Al, B2h, a2v, 0, 0, 0);
      }
      const int r0 = mt * 16 + qd * 4;
#pragma unroll
      for (int r = 0; r < 4; ++r) {
        Vl[r0 + r][ln]      = a0v[r] + bv0;
        Vl[r0 + r][16 + ln] = a1v[r] + bv1;
      }
      if (ln < 4) {
#pragma unroll
        for (int r = 0; r < 4; ++r) ks_l[r0 + r][ln] = a2v[r] + biaskq;
      } else if (ln < 8 && mt == it) {
#pragma unroll
        for (int r = 0; r < 4; ++r) qs_l[qd * 4 + r][ln - 4] = a2v[r] + biaskq;
      }
    }
  }
  __syncthreads();

  // ---------------- phase 2: prep + scores + softmax + attn@V ----------------
  if (tid < kS) {  // K-prep: one j per thread
    const float4 kv = *(const float4*)ks_l[tid];
    const float kmn = fminf(fminf(kv.x, kv.y), fminf(kv.z, kv.w));
    const float kmx = fmaxf(fmaxf(kv.x, kv.y), fmaxf(kv.z, kv.w));
    const float ksc = kPi / (kmx - kmn + 1e-8f);
    kC[0][tid] = cosf((kv.y - kmn) * ksc);
    kC[1][tid] = cosf((kv.z - kmn) * ksc);
    kC[2][tid] = cosf((kv.w - kmn) * ksc);
  } else if (tid < kS + 16) {  // Q-prep: one i per thread
    const int il = tid - kS;
    const float4 qv = *(const float4*)qs_l[il];
    const float qmn = fminf(fminf(qv.x, qv.y), fminf(qv.z, qv.w));
    const float qmx = fmaxf(fmaxf(qv.x, qv.y), fmaxf(qv.z, qv.w));
    const float qsc = kPi / (qmx - qmn + 1e-8f);
    const float qn[3] = {(qv.y - qmn) * qsc, (qv.z - qmn) * qsc, (qv.w - qmn) * qsc};
#pragma unroll
    for (int w = 0; w < 3; ++w) {
      const float th = params[w + 1];
      qA[il][w] = cosf(th) * cosf(qn[w]);
      qB[il][w] = sinf(th) * sinf(qn[w]);
    }
  }
  __syncthreads();

  const int i_loc = tid >> 4;   // 0..15
  const int jl    = tid & 15;   // 16 threads per i-row
  {
    const float A1 = qA[i_loc][0], A2 = qA[i_loc][1], A3 = qA[i_loc][2];
    const float B1 = qB[i_loc][0], B2 = qB[i_loc][1], B3 = qB[i_loc][2];

    float e[8];
    float mx = -1e30f;
#pragma unroll
    for (int jj = 0; jj < 8; ++jj) {
      const int j = jl + 16 * jj;
      const float v = (A1 - B1 * kC[0][j]) * (A2 - B2 * kC[1][j]) *
                      (A3 - B3 * kC[2][j]) * kScale;
      e[jj] = v;
      mx = fmaxf(mx, v);
    }
#pragma unroll
    for (int m = 1; m < 16; m <<= 1) mx = fmaxf(mx, __shfl_xor(mx, m, 16));
    float sum = 0.f;
#pragma unroll
    for (int jj = 0; jj < 8; ++jj) { e[jj] = expf(e[jj] - mx); sum += e[jj]; }
#pragma unroll
    for (int m = 1; m < 16; m <<= 1) sum += __shfl_xor(sum, m, 16);
    const float inv = 1.f / sum;
#pragma unroll
    for (int jj = 0; jj < 8; ++jj) pl[i_loc][jl + 16 * jj] = e[jj] * inv;
  }
  __syncthreads();

  {  // attn @ V: thread -> (i = tid>>4, d0 = tid&15, and d0+16)
    const int d0 = jl;
    float a0 = 0.f, a1 = 0.f;
#pragma unroll 4
    for (int j = 0; j < kS; ++j) {
      const float p = pl[i_loc][j];
      a0 = fmaf(p, Vl[j][d0], a0);
      a1 = fmaf(p, Vl[j][d0 + 16], a1);
    }
    ao_l[i_loc][d0]      = a0;
    ao_l[i_loc][d0 + 16] = a1;
  }
  __syncthreads();

  // ---------------- phase 3: per-head partial out GEMM + atomic accumulate ---
  {
    // A fragment: row ln, k-cols qd*8..qd*8+7 of ao (fp32 -> hi/lo split in regs)
    bf16x8 Ah, Al;
#pragma unroll
    for (int e = 0; e < 8; ++e) {
      const float v = ao_l[ln][qd * 8 + e];
      const __bf16 hi = (__bf16)v;
      Ah[e] = hi;
      Al[e] = (__bf16)(v - (float)hi);
    }
    const int row0 = b * kS + it * 16 + qd * 4;
#pragma unroll
    for (int q = 0; q < 4; ++q) {
      const int col = wave * 64 + q * 16 + ln;
      const float* bp = Wo + col * kK + h * 32 + qd * 8;
      bf16x8 Bh, Bl;
      split8(bp, Bh, Bl);
      f32x4 acc = {0.f, 0.f, 0.f, 0.f};
      acc = __builtin_amdgcn_mfma_f32_16x16x32_bf16(Ah, Bh, acc, 0, 0, 0);
      acc = __builtin_amdgcn_mfma_f32_16x16x32_bf16(Ah, Bl, acc, 0, 0, 0);
      acc = __builtin_amdgcn_mfma_f32_16x16x32_bf16(Al, Bh, acc, 0, 0, 0);
      const float bias = (h == 0) ? bo[col] : 0.f;
#pragma unroll
      for (int r = 0; r < 4; ++r) {
        __hip_atomic_fetch_add(&out[(row0 + r) * kD + col], acc[r] + bias,
                               __ATOMIC_RELAXED, __HIP_MEMORY_SCOPE_AGENT);
      }
    }
  }
}

}  // namespace

extern "C" void kernel_launch(void* const* d_in, const int* in_sizes, int n_in,
                              void* d_out, int out_size, void* d_ws, size_t ws_size,
                              hipStream_t stream) {
  const float* x  = (const float*)d_in[0];
  const float* Wq = (const float*)d_in[1];
  const float* bq = (const float*)d_in[2];
  const float* Wk = (const float*)d_in[3];
  const float* bk = (const float*)d_in[4];
  const float* Wv = (const float*)d_in[5];
  const float* bv = (const float*)d_in[6];
  const float* Wo = (const float*)d_in[7];
  const float* bo = (const float*)d_in[8];
  const float* pr = (const float*)d_in[9];
  float* out = (float*)d_out;

  // out is accumulated atomically across head-blocks -> zero it first.
  hipMemsetAsync(out, 0, out_size, stream);
  fused_one<<<dim3(8, 32), 256, 0, stream>>>(x, Wq, bq, Wk, bk, Wv, bv, Wo, bo,
                                             pr, out);
}

// Round 3
// 95.651 us; speedup vs baseline: 1.6278x; 1.0165x over previous
//
#include <hip/hip_runtime.h>
#include <math.h>

namespace {

constexpr int kS  = 128;
constexpr int kD  = 256;
constexpr int kK  = 256;
constexpr float kPi    = 3.14159265358979323846f;
constexpr float kScale = 0.17677669529663687f;  // 1/sqrt(32)

typedef __bf16 bf16x8 __attribute__((ext_vector_type(8)));
typedef float  f32x4  __attribute__((ext_vector_type(4)));
typedef float  f32x8  __attribute__((ext_vector_type(8)));

// split 8 consecutive fp32 into bf16 hi/lo fragments (in registers)
__device__ inline void split8(const float* __restrict__ p, bf16x8& hi, bf16x8& lo) {
  const f32x8 v = *(const f32x8*)p;
#pragma unroll
  for (int e = 0; e < 8; ++e) {
    const __bf16 h = (__bf16)v[e];
    hi[e] = h;
    lo[e] = (__bf16)(v[e] - (float)h);
  }
}

// ---- single kernel, block = (i-tile, b*8+h), 512 threads (8 waves) ----------
// Phase 1: per-(b,h) QKV sub-projection, 1 m-tile per wave (8 waves <-> 8
//   m-tiles), triple-split bf16 MFMA, results to LDS. Same k-order as before
//   -> bit-identical V/K/Q values.
// Phase 2: angle prep + closed-form scores + softmax + attn@V, remapped to
//   512 threads (32 threads per i-row for scores, one (i,d) per thread for
//   attn@V). ao stays in LDS.
// Phase 3: per-head partial out GEMM (ao_h @ Wo_h^T), bf16 hi/lo split in
//   registers, accumulated into out with device-scope f32 atomics; h==0
//   blocks fold in bias. out zeroed by a memset node first.
__global__ void __launch_bounds__(512) fused_one(
    const float* __restrict__ x,
    const float* __restrict__ Wq, const float* __restrict__ bq,
    const float* __restrict__ Wk, const float* __restrict__ bk,
    const float* __restrict__ Wv, const float* __restrict__ bv,
    const float* __restrict__ Wo, const float* __restrict__ bo,
    const float* __restrict__ params,
    float* __restrict__ out) {
  __shared__ float kC[3][kS];
  __shared__ float Vl[kS][32];
  __shared__ float pl[16][kS + 4];
  __shared__ float qA[16][3], qB[16][3];
  __shared__ float ks_l[kS][4];
  __shared__ float qs_l[16][4];
  __shared__ float ao_l[16][36];   // padded

  const int tid  = threadIdx.x;
  const int wave = tid >> 6;       // 0..7
  const int lane = tid & 63;
  const int ln = lane & 15;
  const int qd = lane >> 4;
  const int it = blockIdx.x;       // 0..7  i-tile
  const int bh = blockIdx.y;       // 0..31
  const int b  = bh >> 3;
  const int h  = bh & 7;

  // ---------------- phase 1: QKV sub-projection (1 m-tile per wave) ---------
  {
    const float* bp0 = Wv + (h * 32 + ln) * kK + qd * 8;
    const float* bp1 = Wv + (h * 32 + 16 + ln) * kK + qd * 8;
    const float* WKQ;
    int wrow;
    float biaskq;
    if (ln < 4)      { WKQ = Wk; wrow = h * 32 + ln;       biaskq = bk[wrow]; }
    else if (ln < 8) { WKQ = Wq; wrow = h * 32 + (ln - 4); biaskq = bq[wrow]; }
    else             { WKQ = Wk; wrow = h * 32 + (ln & 3); biaskq = 0.f; }
    const float* bp2 = WKQ + wrow * kK + qd * 8;
    const float bv0 = bv[h * 32 + ln];
    const float bv1 = bv[h * 32 + 16 + ln];

    const int mt = wave;   // m-tile 0..7
    const float* ap = x + (b * kS + mt * 16 + ln) * kK + qd * 8;
    f32x4 a0v = {0.f, 0.f, 0.f, 0.f};
    f32x4 a1v = {0.f, 0.f, 0.f, 0.f};
    f32x4 a2v = {0.f, 0.f, 0.f, 0.f};
#pragma unroll
    for (int kc = 0; kc < kK; kc += 32) {
      bf16x8 Ah, Al, B0h, B0l, B1h, B1l, B2h, B2l;
      split8(ap + kc, Ah, Al);
      split8(bp0 + kc, B0h, B0l);
      split8(bp1 + kc, B1h, B1l);
      split8(bp2 + kc, B2h, B2l);
      a0v = __builtin_amdgcn_mfma_f32_16x16x32_bf16(Ah, B0h, a0v, 0, 0, 0);
      a0v = __builtin_amdgcn_mfma_f32_16x16x32_bf16(Ah, B0l, a0v, 0, 0, 0);
      a0v = __builtin_amdgcn_mfma_f32_16x16x32_bf16(Al, B0h, a0v, 0, 0, 0);
      a1v = __builtin_amdgcn_mfma_f32_16x16x32_bf16(Ah, B1h, a1v, 0, 0, 0);
      a1v = __builtin_amdgcn_mfma_f32_16x16x32_bf16(Ah, B1l, a1v, 0, 0, 0);
      a1v = __builtin_amdgcn_mfma_f32_16x16x32_bf16(Al, B1h, a1v, 0, 0, 0);
      a2v = __builtin_amdgcn_mfma_f32_16x16x32_bf16(Ah, B2h, a2v, 0, 0, 0);
      a2v = __builtin_amdgcn_mfma_f32_16x16x32_bf16(Ah, B2l, a2v, 0, 0, 0);
      a2v = __builtin_amdgcn_mfma_f32_16x16x32_bf16(Al, B2h, a2v, 0, 0, 0);
    }
    const int r0 = mt * 16 + qd * 4;
#pragma unroll
    for (int r = 0; r < 4; ++r) {
      Vl[r0 + r][ln]      = a0v[r] + bv0;
      Vl[r0 + r][16 + ln] = a1v[r] + bv1;
    }
    if (ln < 4) {
#pragma unroll
      for (int r = 0; r < 4; ++r) ks_l[r0 + r][ln] = a2v[r] + biaskq;
    } else if (ln < 8 && mt == it) {
#pragma unroll
      for (int r = 0; r < 4; ++r) qs_l[qd * 4 + r][ln - 4] = a2v[r] + biaskq;
    }
  }
  __syncthreads();

  // ---------------- phase 2: prep + scores + softmax + attn@V ----------------
  if (tid < kS) {  // K-prep: one j per thread
    const float4 kv = *(const float4*)ks_l[tid];
    const float kmn = fminf(fminf(kv.x, kv.y), fminf(kv.z, kv.w));
    const float kmx = fmaxf(fmaxf(kv.x, kv.y), fmaxf(kv.z, kv.w));
    const float ksc = kPi / (kmx - kmn + 1e-8f);
    kC[0][tid] = cosf((kv.y - kmn) * ksc);
    kC[1][tid] = cosf((kv.z - kmn) * ksc);
    kC[2][tid] = cosf((kv.w - kmn) * ksc);
  } else if (tid < kS + 16) {  // Q-prep: one i per thread
    const int il = tid - kS;
    const float4 qv = *(const float4*)qs_l[il];
    const float qmn = fminf(fminf(qv.x, qv.y), fminf(qv.z, qv.w));
    const float qmx = fmaxf(fmaxf(qv.x, qv.y), fmaxf(qv.z, qv.w));
    const float qsc = kPi / (qmx - qmn + 1e-8f);
    const float qn[3] = {(qv.y - qmn) * qsc, (qv.z - qmn) * qsc, (qv.w - qmn) * qsc};
#pragma unroll
    for (int w = 0; w < 3; ++w) {
      const float th = params[w + 1];
      qA[il][w] = cosf(th) * cosf(qn[w]);
      qB[il][w] = sinf(th) * sinf(qn[w]);
    }
  }
  __syncthreads();

  const int i_loc = tid >> 5;   // 0..15
  const int jl    = tid & 31;   // 32 threads per i-row
  {
    const float A1 = qA[i_loc][0], A2 = qA[i_loc][1], A3 = qA[i_loc][2];
    const float B1 = qB[i_loc][0], B2 = qB[i_loc][1], B3 = qB[i_loc][2];

    float e[4];
    float mx = -1e30f;
#pragma unroll
    for (int jj = 0; jj < 4; ++jj) {
      const int j = jl + 32 * jj;
      const float v = (A1 - B1 * kC[0][j]) * (A2 - B2 * kC[1][j]) *
                      (A3 - B3 * kC[2][j]) * kScale;
      e[jj] = v;
      mx = fmaxf(mx, v);
    }
#pragma unroll
    for (int m = 1; m < 32; m <<= 1) mx = fmaxf(mx, __shfl_xor(mx, m, 32));
    float sum = 0.f;
#pragma unroll
    for (int jj = 0; jj < 4; ++jj) { e[jj] = expf(e[jj] - mx); sum += e[jj]; }
#pragma unroll
    for (int m = 1; m < 32; m <<= 1) sum += __shfl_xor(sum, m, 32);
    const float inv = 1.f / sum;
#pragma unroll
    for (int jj = 0; jj < 4; ++jj) pl[i_loc][jl + 32 * jj] = e[jj] * inv;
  }
  __syncthreads();

  {  // attn @ V: one (i, d) per thread
    const int d = jl;
    float a = 0.f;
#pragma unroll 8
    for (int j = 0; j < kS; ++j)
      a = fmaf(pl[i_loc][j], Vl[j][d], a);
    ao_l[i_loc][d] = a;
  }
  __syncthreads();

  // ---------------- phase 3: per-head partial out GEMM + atomic accumulate ---
  {
    bf16x8 Ah, Al;
#pragma unroll
    for (int e = 0; e < 8; ++e) {
      const float v = ao_l[ln][qd * 8 + e];
      const __bf16 hi = (__bf16)v;
      Ah[e] = hi;
      Al[e] = (__bf16)(v - (float)hi);
    }
    const int row0 = b * kS + it * 16 + qd * 4;
#pragma unroll
    for (int q = 0; q < 2; ++q) {
      const int col = wave * 32 + q * 16 + ln;
      const float* bp = Wo + col * kK + h * 32 + qd * 8;
      bf16x8 Bh, Bl;
      split8(bp, Bh, Bl);
      f32x4 acc = {0.f, 0.f, 0.f, 0.f};
      acc = __builtin_amdgcn_mfma_f32_16x16x32_bf16(Ah, Bh, acc, 0, 0, 0);
      acc = __builtin_amdgcn_mfma_f32_16x16x32_bf16(Ah, Bl, acc, 0, 0, 0);
      acc = __builtin_amdgcn_mfma_f32_16x16x32_bf16(Al, Bh, acc, 0, 0, 0);
      const float bias = (h == 0) ? bo[col] : 0.f;
#pragma unroll
      for (int r = 0; r < 4; ++r) {
        __hip_atomic_fetch_add(&out[(row0 + r) * kD + col], acc[r] + bias,
                               __ATOMIC_RELAXED, __HIP_MEMORY_SCOPE_AGENT);
      }
    }
  }
}

}  // namespace

extern "C" void kernel_launch(void* const* d_in, const int* in_sizes, int n_in,
                              void* d_out, int out_size, void* d_ws, size_t ws_size,
                              hipStream_t stream) {
  const float* x  = (const float*)d_in[0];
  const float* Wq = (const float*)d_in[1];
  const float* bq = (const float*)d_in[2];
  const float* Wk = (const float*)d_in[3];
  const float* bk = (const float*)d_in[4];
  const float* Wv = (const float*)d_in[5];
  const float* bv = (const float*)d_in[6];
  const float* Wo = (const float*)d_in[7];
  const float* bo = (const float*)d_in[8];
  const float* pr = (const float*)d_in[9];
  float* out = (float*)d_out;

  // out is accumulated atomically across head-blocks -> zero it first.
  hipMemsetAsync(out, 0, out_size, stream);
  fused_one<<<dim3(8, 32), 512, 0, stream>>>(x, Wq, bq, Wk, bk, Wv, bv, Wo, bo,
                                             pr, out);
}

// Round 4
// 87.564 us; speedup vs baseline: 1.7782x; 1.0924x over previous
//
#include <hip/hip_runtime.h>
#include <math.h>

namespace {

constexpr int kS  = 128;
constexpr int kD  = 256;
constexpr int kK  = 256;
constexpr float kPi    = 3.14159265358979323846f;
constexpr float kScale = 0.17677669529663687f;  // 1/sqrt(32)

typedef __bf16 bf16x8 __attribute__((ext_vector_type(8)));
typedef float  f32x4  __attribute__((ext_vector_type(4)));
typedef float  f32x8  __attribute__((ext_vector_type(8)));

// split 8 consecutive fp32 into bf16 hi/lo fragments (in registers)
__device__ inline void split8(const float* __restrict__ p, bf16x8& hi, bf16x8& lo) {
  const f32x8 v = *(const f32x8*)p;
#pragma unroll
  for (int e = 0; e < 8; ++e) {
    const __bf16 h = (__bf16)v[e];
    hi[e] = h;
    lo[e] = (__bf16)(v[e] - (float)h);
  }
}

// ---- K1: QKV projection via bf16x3 MFMA (R0-proven, computed exactly once) --
// grid (32 m-tiles, 5): ny<4 -> V cols ny*64+wave*16+ln (full 256 cols of Wv);
// ny==4 -> compact Qsub/Ksub: wave0/1 = Qsub cols 0..31, wave2/3 = Ksub,
//          compact col c maps to weight row head*32+wire (head=c>>2, wire=c&3).
__global__ void qkv_kernel(const float* __restrict__ x,
                           const float* __restrict__ Wq, const float* __restrict__ bq,
                           const float* __restrict__ Wk, const float* __restrict__ bk,
                           const float* __restrict__ Wv, const float* __restrict__ bv,
                           float* __restrict__ V, float* __restrict__ Qs,
                           float* __restrict__ Ks) {
  const int wave = threadIdx.x >> 6;
  const int lane = threadIdx.x & 63;
  const int ln = lane & 15;
  const int qd = lane >> 4;
  const int m0 = blockIdx.x * 16;
  const int ny = blockIdx.y;

  const float* W;
  const float* bias;
  int wrow;
  if (ny < 4) {
    W = Wv; bias = bv;
    wrow = ny * 64 + wave * 16 + ln;
  } else {
    const int c = (wave & 1) * 16 + ln;   // compact col 0..31
    wrow = (c >> 2) * 32 + (c & 3);       // head*32 + wire
    if (wave < 2) { W = Wq; bias = bq; } else { W = Wk; bias = bk; }
  }

  const float* ap = x + (m0 + ln) * kK + qd * 8;
  const float* bp = W + wrow * kK + qd * 8;

  f32x4 acc = {0.f, 0.f, 0.f, 0.f};
#pragma unroll
  for (int kc = 0; kc < kK; kc += 32) {
    bf16x8 Ah, Al, Bh, Bl;
    split8(ap + kc, Ah, Al);
    split8(bp + kc, Bh, Bl);
    acc = __builtin_amdgcn_mfma_f32_16x16x32_bf16(Ah, Bh, acc, 0, 0, 0);
    acc = __builtin_amdgcn_mfma_f32_16x16x32_bf16(Ah, Bl, acc, 0, 0, 0);
    acc = __builtin_amdgcn_mfma_f32_16x16x32_bf16(Al, Bh, acc, 0, 0, 0);
  }
  const float bvv = bias[wrow];
  const int row0 = m0 + qd * 4;
  if (ny < 4) {
    const int col = ny * 64 + wave * 16 + ln;
#pragma unroll
    for (int r = 0; r < 4; ++r)
      V[(row0 + r) * kD + col] = acc[r] + bvv;
  } else {
    const int c = (wave & 1) * 16 + ln;
    float* o = (wave < 2) ? Qs : Ks;
#pragma unroll
    for (int r = 0; r < 4; ++r)
      o[(row0 + r) * 32 + c] = acc[r] + bvv;
  }
}

// ---- K2: fused prep + scores + softmax + attn@V + per-head out GEMM --------
// Phases 2-3 of the R3 kernel (harness-validated): ao stays in LDS, per-head
// 16x256 partial of out = ao_h @ Wo_h^T accumulated with device-scope f32
// atomics (h==0 blocks fold in bias). grid (8 i-tiles, 32 bh), 256 threads.
__global__ void __launch_bounds__(256) fused_attn_out(
    const float* __restrict__ Qs, const float* __restrict__ Ks,
    const float* __restrict__ V,  const float* __restrict__ params,
    const float* __restrict__ Wo, const float* __restrict__ bo,
    float* __restrict__ out) {
  __shared__ float kC[3][kS];
  __shared__ float Vl[kS][32];
  __shared__ float pl[16][kS + 4];
  __shared__ float qA[16][3], qB[16][3];
  __shared__ float ao_l[16][36];   // padded

  const int bh = blockIdx.y;
  const int i0 = blockIdx.x * 16;
  const int b  = bh >> 3;
  const int h  = bh & 7;
  const int tid = threadIdx.x;
  const int wave = tid >> 6;
  const int lane = tid & 63;
  const int ln = lane & 15;
  const int qd = lane >> 4;

  if (tid < kS) {  // K-prep: one j per thread
    const float4 kv = *(const float4*)(Ks + (b * kS + tid) * 32 + h * 4);
    const float kmn = fminf(fminf(kv.x, kv.y), fminf(kv.z, kv.w));
    const float kmx = fmaxf(fmaxf(kv.x, kv.y), fmaxf(kv.z, kv.w));
    const float ksc = kPi / (kmx - kmn + 1e-8f);
    kC[0][tid] = cosf((kv.y - kmn) * ksc);
    kC[1][tid] = cosf((kv.z - kmn) * ksc);
    kC[2][tid] = cosf((kv.w - kmn) * ksc);
  } else if (tid < kS + 16) {  // Q-prep: one i per thread
    const int il = tid - kS;
    const float4 qv = *(const float4*)(Qs + (b * kS + i0 + il) * 32 + h * 4);
    const float qmn = fminf(fminf(qv.x, qv.y), fminf(qv.z, qv.w));
    const float qmx = fmaxf(fmaxf(qv.x, qv.y), fmaxf(qv.z, qv.w));
    const float qsc = kPi / (qmx - qmn + 1e-8f);
    const float qn[3] = {(qv.y - qmn) * qsc, (qv.z - qmn) * qsc, (qv.w - qmn) * qsc};
#pragma unroll
    for (int w = 0; w < 3; ++w) {
      const float th = params[w + 1];
      qA[il][w] = cosf(th) * cosf(qn[w]);
      qB[il][w] = sinf(th) * sinf(qn[w]);
    }
  }
  {  // V tile load (all threads)
    const int j0 = tid >> 5, d = tid & 31;
#pragma unroll
    for (int r = 0; r < 16; ++r) {
      const int j = r * 8 + j0;
      Vl[j][d] = V[(b * kS + j) * kD + h * 32 + d];
    }
  }
  __syncthreads();

  const int i_loc = tid >> 4;   // 0..15
  const int jl    = tid & 15;   // 16 threads per i-row
  {
    const float A1 = qA[i_loc][0], A2 = qA[i_loc][1], A3 = qA[i_loc][2];
    const float B1 = qB[i_loc][0], B2 = qB[i_loc][1], B3 = qB[i_loc][2];

    float e[8];
    float mx = -1e30f;
#pragma unroll
    for (int jj = 0; jj < 8; ++jj) {
      const int j = jl + 16 * jj;
      const float v = (A1 - B1 * kC[0][j]) * (A2 - B2 * kC[1][j]) *
                      (A3 - B3 * kC[2][j]) * kScale;
      e[jj] = v;
      mx = fmaxf(mx, v);
    }
#pragma unroll
    for (int m = 1; m < 16; m <<= 1) mx = fmaxf(mx, __shfl_xor(mx, m, 16));
    float sum = 0.f;
#pragma unroll
    for (int jj = 0; jj < 8; ++jj) { e[jj] = expf(e[jj] - mx); sum += e[jj]; }
#pragma unroll
    for (int m = 1; m < 16; m <<= 1) sum += __shfl_xor(sum, m, 16);
    const float inv = 1.f / sum;
#pragma unroll
    for (int jj = 0; jj < 8; ++jj) pl[i_loc][jl + 16 * jj] = e[jj] * inv;
  }
  __syncthreads();

  {  // attn @ V: thread -> (i = tid>>4, d0 = tid&15, and d0+16)
    const int d0 = jl;
    float a0 = 0.f, a1 = 0.f;
#pragma unroll 4
    for (int j = 0; j < kS; ++j) {
      const float p = pl[i_loc][j];
      a0 = fmaf(p, Vl[j][d0], a0);
      a1 = fmaf(p, Vl[j][d0 + 16], a1);
    }
    ao_l[i_loc][d0]      = a0;
    ao_l[i_loc][d0 + 16] = a1;
  }
  __syncthreads();

  // ---- per-head partial out GEMM + atomic accumulate ----
  {
    bf16x8 Ah, Al;
#pragma unroll
    for (int e = 0; e < 8; ++e) {
      const float v = ao_l[ln][qd * 8 + e];
      const __bf16 hi = (__bf16)v;
      Ah[e] = hi;
      Al[e] = (__bf16)(v - (float)hi);
    }
    const int row0 = b * kS + i0 + qd * 4;
#pragma unroll
    for (int q = 0; q < 4; ++q) {
      const int col = wave * 64 + q * 16 + ln;
      const float* bp = Wo + col * kK + h * 32 + qd * 8;
      bf16x8 Bh, Bl;
      split8(bp, Bh, Bl);
      f32x4 acc = {0.f, 0.f, 0.f, 0.f};
      acc = __builtin_amdgcn_mfma_f32_16x16x32_bf16(Ah, Bh, acc, 0, 0, 0);
      acc = __builtin_amdgcn_mfma_f32_16x16x32_bf16(Ah, Bl, acc, 0, 0, 0);
      acc = __builtin_amdgcn_mfma_f32_16x16x32_bf16(Al, Bh, acc, 0, 0, 0);
      const float bias = (h == 0) ? bo[col] : 0.f;
#pragma unroll
      for (int r = 0; r < 4; ++r) {
        __hip_atomic_fetch_add(&out[(row0 + r) * kD + col], acc[r] + bias,
                               __ATOMIC_RELAXED, __HIP_MEMORY_SCOPE_AGENT);
      }
    }
  }
}

}  // namespace

extern "C" void kernel_launch(void* const* d_in, const int* in_sizes, int n_in,
                              void* d_out, int out_size, void* d_ws, size_t ws_size,
                              hipStream_t stream) {
  const float* x  = (const float*)d_in[0];
  const float* Wq = (const float*)d_in[1];
  const float* bq = (const float*)d_in[2];
  const float* Wk = (const float*)d_in[3];
  const float* bk = (const float*)d_in[4];
  const float* Wv = (const float*)d_in[5];
  const float* bv = (const float*)d_in[6];
  const float* Wo = (const float*)d_in[7];
  const float* bo = (const float*)d_in[8];
  const float* pr = (const float*)d_in[9];
  float* out = (float*)d_out;

  // -------- workspace layout (floats), all dedicated, no aliasing --------
  float* ws = (float*)d_ws;
  float* V   = ws;               // 131072
  float* Qs  = V + 131072;       // 16384 ([512][32] compact head-wire cols)
  float* Ks  = Qs + 16384;       // 16384
  // total ~0.64 MB << ws_size

  // out accumulated atomically across head-blocks -> zero it first (tiny).
  hipMemsetAsync(out, 0, out_size, stream);
  qkv_kernel<<<dim3(32, 5), 256, 0, stream>>>(x, Wq, bq, Wk, bk, Wv, bv, V, Qs, Ks);
  fused_attn_out<<<dim3(8, 32), 256, 0, stream>>>(Qs, Ks, V, pr, Wo, bo, out);
}

// Round 5
// 85.178 us; speedup vs baseline: 1.8280x; 1.0280x over previous
//
#include <hip/hip_runtime.h>
#include <math.h>

namespace {

constexpr int kS  = 128;
constexpr int kD  = 256;
constexpr int kK  = 256;
constexpr float kPi    = 3.14159265358979323846f;
constexpr float kScale = 0.17677669529663687f;  // 1/sqrt(32)

typedef __bf16 bf16x8 __attribute__((ext_vector_type(8)));
typedef float  f32x4  __attribute__((ext_vector_type(4)));
typedef float  f32x8  __attribute__((ext_vector_type(8)));

// split 8 consecutive fp32 into bf16 hi/lo fragments (in registers)
__device__ inline void split8(const float* __restrict__ p, bf16x8& hi, bf16x8& lo) {
  const f32x8 v = *(const f32x8*)p;
#pragma unroll
  for (int e = 0; e < 8; ++e) {
    const __bf16 h = (__bf16)v[e];
    hi[e] = h;
    lo[e] = (__bf16)(v[e] - (float)h);
  }
}

// ---- K1: QKV projection via bf16x3 MFMA + fold-in zeroing of `out` ---------
// grid (32 m-tiles, 5): ny<4 -> V cols ny*64+wave*16+ln (full 256 cols of Wv);
// ny==4 -> compact Qsub/Ksub: wave0/1 = Qsub cols 0..31, wave2/3 = Ksub,
//          compact col c maps to weight row head*32+wire (head=c>>2, wire=c&3).
// Also zeroes `out` (32768 float4 spread over the first 32768 threads) --
// stream order guarantees completion before K2's atomics start.
__global__ void qkv_kernel(const float* __restrict__ x,
                           const float* __restrict__ Wq, const float* __restrict__ bq,
                           const float* __restrict__ Wk, const float* __restrict__ bk,
                           const float* __restrict__ Wv, const float* __restrict__ bv,
                           float* __restrict__ V, float* __restrict__ Qs,
                           float* __restrict__ Ks, float* __restrict__ out) {
  // ---- zero `out` (graph-replay safe: runs every launch, before K2) ----
  {
    const int gid = (blockIdx.y * 32 + blockIdx.x) * 256 + threadIdx.x;
    if (gid < (kS * 4 * kD) / 4) {
      ((f32x4*)out)[gid] = (f32x4){0.f, 0.f, 0.f, 0.f};
    }
  }

  const int wave = threadIdx.x >> 6;
  const int lane = threadIdx.x & 63;
  const int ln = lane & 15;
  const int qd = lane >> 4;
  const int m0 = blockIdx.x * 16;
  const int ny = blockIdx.y;

  const float* W;
  const float* bias;
  int wrow;
  if (ny < 4) {
    W = Wv; bias = bv;
    wrow = ny * 64 + wave * 16 + ln;
  } else {
    const int c = (wave & 1) * 16 + ln;   // compact col 0..31
    wrow = (c >> 2) * 32 + (c & 3);       // head*32 + wire
    if (wave < 2) { W = Wq; bias = bq; } else { W = Wk; bias = bk; }
  }

  const float* ap = x + (m0 + ln) * kK + qd * 8;
  const float* bp = W + wrow * kK + qd * 8;

  f32x4 acc = {0.f, 0.f, 0.f, 0.f};
#pragma unroll
  for (int kc = 0; kc < kK; kc += 32) {
    bf16x8 Ah, Al, Bh, Bl;
    split8(ap + kc, Ah, Al);
    split8(bp + kc, Bh, Bl);
    acc = __builtin_amdgcn_mfma_f32_16x16x32_bf16(Ah, Bh, acc, 0, 0, 0);
    acc = __builtin_amdgcn_mfma_f32_16x16x32_bf16(Ah, Bl, acc, 0, 0, 0);
    acc = __builtin_amdgcn_mfma_f32_16x16x32_bf16(Al, Bh, acc, 0, 0, 0);
  }
  const float bvv = bias[wrow];
  const int row0 = m0 + qd * 4;
  if (ny < 4) {
    const int col = ny * 64 + wave * 16 + ln;
#pragma unroll
    for (int r = 0; r < 4; ++r)
      V[(row0 + r) * kD + col] = acc[r] + bvv;
  } else {
    const int c = (wave & 1) * 16 + ln;
    float* o = (wave < 2) ? Qs : Ks;
#pragma unroll
    for (int r = 0; r < 4; ++r)
      o[(row0 + r) * 32 + c] = acc[r] + bvv;
  }
}

// ---- K2: fused prep + scores + softmax + attn@V + per-head out GEMM --------
// ao stays in LDS; per-head 16x256 partial of out = ao_h @ Wo_h^T accumulated
// with device-scope f32 atomics (h==0 blocks fold in bias).
// grid (8 i-tiles, 32 bh), 256 threads.
__global__ void __launch_bounds__(256) fused_attn_out(
    const float* __restrict__ Qs, const float* __restrict__ Ks,
    const float* __restrict__ V,  const float* __restrict__ params,
    const float* __restrict__ Wo, const float* __restrict__ bo,
    float* __restrict__ out) {
  __shared__ float kC[3][kS];
  __shared__ float Vl[kS][32];
  __shared__ float pl[16][kS + 4];
  __shared__ float qA[16][3], qB[16][3];
  __shared__ float ao_l[16][36];   // padded

  const int bh = blockIdx.y;
  const int i0 = blockIdx.x * 16;
  const int b  = bh >> 3;
  const int h  = bh & 7;
  const int tid = threadIdx.x;
  const int wave = tid >> 6;
  const int lane = tid & 63;
  const int ln = lane & 15;
  const int qd = lane >> 4;

  if (tid < kS) {  // K-prep: one j per thread
    const float4 kv = *(const float4*)(Ks + (b * kS + tid) * 32 + h * 4);
    const float kmn = fminf(fminf(kv.x, kv.y), fminf(kv.z, kv.w));
    const float kmx = fmaxf(fmaxf(kv.x, kv.y), fmaxf(kv.z, kv.w));
    const float ksc = kPi / (kmx - kmn + 1e-8f);
    kC[0][tid] = cosf((kv.y - kmn) * ksc);
    kC[1][tid] = cosf((kv.z - kmn) * ksc);
    kC[2][tid] = cosf((kv.w - kmn) * ksc);
  } else if (tid < kS + 16) {  // Q-prep: one i per thread
    const int il = tid - kS;
    const float4 qv = *(const float4*)(Qs + (b * kS + i0 + il) * 32 + h * 4);
    const float qmn = fminf(fminf(qv.x, qv.y), fminf(qv.z, qv.w));
    const float qmx = fmaxf(fmaxf(qv.x, qv.y), fmaxf(qv.z, qv.w));
    const float qsc = kPi / (qmx - qmn + 1e-8f);
    const float qn[3] = {(qv.y - qmn) * qsc, (qv.z - qmn) * qsc, (qv.w - qmn) * qsc};
#pragma unroll
    for (int w = 0; w < 3; ++w) {
      const float th = params[w + 1];
      qA[il][w] = cosf(th) * cosf(qn[w]);
      qB[il][w] = sinf(th) * sinf(qn[w]);
    }
  }
  {  // V tile load, coalesced float4: thread -> row j, 4-col group
    const int g  = tid & 7;          // float4 index within a 32-col row
    const int jb = tid >> 3;         // 0..31: row within a 32-row group
#pragma unroll
    for (int r = 0; r < 4; ++r) {
      const int j = r * 32 + jb;
      const float4 v = *(const float4*)(V + (b * kS + j) * kD + h * 32 + g * 4);
      *(float4*)&Vl[j][g * 4] = v;
    }
  }
  __syncthreads();

  const int i_loc = tid >> 4;   // 0..15
  const int jl    = tid & 15;   // 16 threads per i-row
  {
    const float A1 = qA[i_loc][0], A2 = qA[i_loc][1], A3 = qA[i_loc][2];
    const float B1 = qB[i_loc][0], B2 = qB[i_loc][1], B3 = qB[i_loc][2];

    float e[8];
    float mx = -1e30f;
#pragma unroll
    for (int jj = 0; jj < 8; ++jj) {
      const int j = jl + 16 * jj;
      const float v = (A1 - B1 * kC[0][j]) * (A2 - B2 * kC[1][j]) *
                      (A3 - B3 * kC[2][j]) * kScale;
      e[jj] = v;
      mx = fmaxf(mx, v);
    }
#pragma unroll
    for (int m = 1; m < 16; m <<= 1) mx = fmaxf(mx, __shfl_xor(mx, m, 16));
    float sum = 0.f;
#pragma unroll
    for (int jj = 0; jj < 8; ++jj) { e[jj] = expf(e[jj] - mx); sum += e[jj]; }
#pragma unroll
    for (int m = 1; m < 16; m <<= 1) sum += __shfl_xor(sum, m, 16);
    const float inv = 1.f / sum;
#pragma unroll
    for (int jj = 0; jj < 8; ++jj) pl[i_loc][jl + 16 * jj] = e[jj] * inv;
  }
  __syncthreads();

  {  // attn @ V: thread -> (i = tid>>4, d0 = tid&15, and d0+16)
    const int d0 = jl;
    float a0 = 0.f, a1 = 0.f;
#pragma unroll 4
    for (int j = 0; j < kS; ++j) {
      const float p = pl[i_loc][j];
      a0 = fmaf(p, Vl[j][d0], a0);
      a1 = fmaf(p, Vl[j][d0 + 16], a1);
    }
    ao_l[i_loc][d0]      = a0;
    ao_l[i_loc][d0 + 16] = a1;
  }
  __syncthreads();

  // ---- per-head partial out GEMM + atomic accumulate ----
  {
    bf16x8 Ah, Al;
#pragma unroll
    for (int e = 0; e < 8; ++e) {
      const float v = ao_l[ln][qd * 8 + e];
      const __bf16 hi = (__bf16)v;
      Ah[e] = hi;
      Al[e] = (__bf16)(v - (float)hi);
    }
    const int row0 = b * kS + i0 + qd * 4;
#pragma unroll
    for (int q = 0; q < 4; ++q) {
      const int col = wave * 64 + q * 16 + ln;
      const float* bp = Wo + col * kK + h * 32 + qd * 8;
      bf16x8 Bh, Bl;
      split8(bp, Bh, Bl);
      f32x4 acc = {0.f, 0.f, 0.f, 0.f};
      acc = __builtin_amdgcn_mfma_f32_16x16x32_bf16(Ah, Bh, acc, 0, 0, 0);
      acc = __builtin_amdgcn_mfma_f32_16x16x32_bf16(Ah, Bl, acc, 0, 0, 0);
      acc = __builtin_amdgcn_mfma_f32_16x16x32_bf16(Al, Bh, acc, 0, 0, 0);
      const float bias = (h == 0) ? bo[col] : 0.f;
#pragma unroll
      for (int r = 0; r < 4; ++r) {
        __hip_atomic_fetch_add(&out[(row0 + r) * kD + col], acc[r] + bias,
                               __ATOMIC_RELAXED, __HIP_MEMORY_SCOPE_AGENT);
      }
    }
  }
}

}  // namespace

extern "C" void kernel_launch(void* const* d_in, const int* in_sizes, int n_in,
                              void* d_out, int out_size, void* d_ws, size_t ws_size,
                              hipStream_t stream) {
  const float* x  = (const float*)d_in[0];
  const float* Wq = (const float*)d_in[1];
  const float* bq = (const float*)d_in[2];
  const float* Wk = (const float*)d_in[3];
  const float* bk = (const float*)d_in[4];
  const float* Wv = (const float*)d_in[5];
  const float* bv = (const float*)d_in[6];
  const float* Wo = (const float*)d_in[7];
  const float* bo = (const float*)d_in[8];
  const float* pr = (const float*)d_in[9];
  float* out = (float*)d_out;

  // -------- workspace layout (floats), all dedicated, no aliasing --------
  float* ws = (float*)d_ws;
  float* V   = ws;               // 131072
  float* Qs  = V + 131072;       // 16384 ([512][32] compact head-wire cols)
  float* Ks  = Qs + 16384;       // 16384
  // total ~0.64 MB << ws_size

  // K1 zeroes `out` itself (stream-ordered before K2's atomics) -> 2 nodes.
  qkv_kernel<<<dim3(32, 5), 256, 0, stream>>>(x, Wq, bq, Wk, bk, Wv, bv,
                                              V, Qs, Ks, out);
  fused_attn_out<<<dim3(8, 32), 256, 0, stream>>>(Qs, Ks, V, pr, Wo, bo, out);
}